// Round 8
// baseline (215.717 us; speedup 1.0000x reference)
//
#include <hip/hip_runtime.h>

#define CIN    128
#define HH     56
#define WW_    56
#define NBATCH 32
#define COUT   256
#define KTOT   1152          // 9 taps * 128 ci  (k-order: kh, kw, ci)
#define PLANE  3136          // 56*56
#define HP     58            // padded H/W
#define BM     128           // c_out tile
#define BN     128           // pixel tile
#define BK     64            // k per step (always within one tap: 1152 = 9*128)
#define NXROWS (NBATCH * HP) // 1856 x-prep blocks
#define NWG    ((NBATCH * PLANE / BN) * (COUT / BM))   // 1568, % 8 == 0
#define CHUNK  (NWG / 8)                               // 196 logical ids per XCD

#define WB_OFF   0                         // bf16 weights [256][9][128] in ws
#define XP_OFF   (1u << 20)                // padded bf16 input [32][58][58][128]

typedef __attribute__((ext_vector_type(8))) short bf16x8;
typedef __attribute__((ext_vector_type(16))) float f32x16;

__device__ __forceinline__ unsigned short f2bf(float f) {
    unsigned int u = __builtin_bit_cast(unsigned int, f);
    u += 0x7fffu + ((u >> 16) & 1u);   // RNE
    return (unsigned short)(u >> 16);
}

__device__ __forceinline__ void gl_lds16(const void* g, void* l) {
    __builtin_amdgcn_global_load_lds(
        (const __attribute__((address_space(1))) void*)g,
        (__attribute__((address_space(3))) void*)l, 16, 0, 0);
}

// ---- fused pre-pass (unchanged, verified): blocks [0,1856) input rows,
// blocks [1856,2112) weights. ----
__global__ __launch_bounds__(256)
void prep(const float* __restrict__ in, const float* __restrict__ w,
          unsigned short* __restrict__ xp, unsigned short* __restrict__ wb) {
    __shared__ __align__(16) unsigned short Lx[16 * 456];   // 14592 B
    __shared__ __align__(16) unsigned short Lw[KTOT];       //  2304 B

    const int b = blockIdx.x;
    const int t = threadIdx.x;

    if (b >= NXROWS) {
        const int o = b - NXROWS;
        const float4* src = (const float4*)(w + (size_t)o * KTOT);   // 288 float4
        #pragma unroll
        for (int e = 0; e < 2; ++e) {
            const int q = t + e * 256;
            if (q < 288) {
                const float4 v = src[q];
                #pragma unroll
                for (int u = 0; u < 4; ++u) {
                    const int idx = q * 4 + u;       // = ci*9 + tap
                    const int ci  = idx / 9;
                    const int tap = idx - ci * 9;
                    Lw[tap * 128 + ci] = f2bf(((const float*)&v)[u]);
                }
            }
        }
        __syncthreads();
        if (t < 144)
            ((uint4*)(wb + (size_t)o * KTOT))[t] = ((const uint4*)Lw)[t];
        return;
    }

    const int n  = b / HP;
    const int ho = b - n * HP;
    uint4* orow = (uint4*)(xp + (((size_t)n * HP + ho) * HP) * CIN);  // 928 uint4

    if (ho == 0 || ho == HP - 1) {
        #pragma unroll
        for (int e = 0; e < 4; ++e) {
            const int idx = t + e * 256;
            if (idx < 928) orow[idx] = (uint4){0u, 0u, 0u, 0u};
        }
        return;
    }

    const int h = ho - 1;
    {
        const int ci = t >> 1;                       // 0..127
        const int w0 = (t & 1) * 28;                 // two half-rows
        const float4* ib = (const float4*)(in + ((size_t)n * CIN + ci) * PLANE
                                              + (size_t)h * WW_ + w0);
        unsigned short* Lp = &Lx[(ci >> 3) * 456 + w0 * 8 + (ci & 7)];
        #pragma unroll
        for (int q = 0; q < 7; ++q) {                // 7 x float4 = 28 floats
            const float4 v = ib[q];
            Lp[(q * 4 + 0) * 8] = f2bf(v.x);
            Lp[(q * 4 + 1) * 8] = f2bf(v.y);
            Lp[(q * 4 + 2) * 8] = f2bf(v.z);
            Lp[(q * 4 + 3) * 8] = f2bf(v.w);
        }
    }
    __syncthreads();

    #pragma unroll
    for (int e = 0; e < 4; ++e) {
        const int idx = t + e * 256;                 // uint4 index within row
        if (idx < 928) {
            const int wo = idx >> 4;                 // pixel 0..57
            const int ch = idx & 15;                 // 8-ci chunk
            uint4 pk = (uint4){0u, 0u, 0u, 0u};
            if (wo >= 1 && wo <= WW_)
                pk = *(const uint4*)&Lx[ch * 456 + (wo - 1) * 8];  // 16B-aligned
            orow[idx] = pk;
        }
    }
}

// ---- main: implicit-GEMM conv — R6 verified structure (T1 XCD swizzle,
// same staging/swizzle/barriers), MFMA shape switched 16x16x32 -> 32x32x16
// (µbench +15% rate, half the issue slots). Per wave: 2x2 tiles of 32x32,
// acc = f32x16[2][2] (64 AGPR, unchanged). Fragment: lane l holds 8
// contiguous ci at row/col l&31, k-half l>>5; per-quarter LDS read pattern
// (fixed chunk, key=row&7) identical to the verified 0-conflict kernel.
// C/D: col=lane&31, row=(reg&3)+8*(reg>>2)+4*(lane>>5)  [m74/m101]. ----
__global__ __launch_bounds__(256, 2)
void conv_mfma(const unsigned short* __restrict__ wb,
               const unsigned short* __restrict__ xp,
               const float* __restrict__ bias,
               float* __restrict__ out)
{
    __shared__ __align__(16) unsigned short Asm_[BM * BK];  // 16 KB, rows of 128B
    __shared__ __align__(16) unsigned short Bsm_[BN * BK];  // 16 KB

    const int t = threadIdx.x;

    // bijective XCD-chunked swizzle (NWG % 8 == 0), c0-pair adjacency
    const int logical = (blockIdx.x & 7) * CHUNK + (blockIdx.x >> 3);
    const int pix0 = (logical >> 1) * BN;
    const int c0   = (logical & 1) * BM;

    const int slot = t & 7;
    const int r32  = t >> 3;                 // 0..31
    const int swiz = (slot ^ (r32 & 7)) * 16;

    const char* aBase = (const char*)wb + (size_t)(c0 + r32) * (KTOT * 2) + swiz;
    const char* bBase[4];
    #pragma unroll
    for (int p = 0; p < 4; ++p) {
        const int pix = pix0 + r32 + p * 32;
        const int n   = pix / PLANE;
        const int rem = pix - n * PLANE;
        const int h   = rem / WW_;
        const int w   = rem - h * WW_;
        bBase[p] = (const char*)xp + ((size_t)(n * HP + h) * HP + w) * (CIN * 2) + swiz;
    }

    const int lane  = t & 63;
    const int wave  = t >> 6;
    const int wm    = (wave & 1) * 64;
    const int wn    = (wave >> 1) * 64;
    const int l31   = lane & 31;
    const int khalf = lane >> 5;             // k-half within 16-k MFMA step
    const int rmod  = lane & 7;              // swizzle key (= row&7 of frag row)

    f32x16 acc[2][2];
    #pragma unroll
    for (int i = 0; i < 2; ++i)
        #pragma unroll
        for (int j = 0; j < 2; ++j)
            acc[i][j] = (f32x16){0.f};

    char* const asmb = (char*)Asm_;
    char* const bsmb = (char*)Bsm_;

    for (int tap = 0; tap < 9; ++tap) {
        const int toff = ((tap / 3) * HP + (tap % 3)) * (CIN * 2);
        for (int ci0b = 0; ci0b < 256; ci0b += 128) {
            const int abyte = tap * 256 + ci0b;
            #pragma unroll
            for (int p = 0; p < 4; ++p)
                gl_lds16(aBase + (size_t)p * 32 * (KTOT * 2) + abyte, asmb + p * 4096 + t * 16);
            #pragma unroll
            for (int p = 0; p < 4; ++p)
                gl_lds16(bBase[p] + toff + ci0b, bsmb + p * 4096 + t * 16);
            __syncthreads();

            bf16x8 af[2][4], bfr[2][4];
            #pragma unroll
            for (int kq = 0; kq < 4; ++kq) {
                const int phys = ((kq * 2 + khalf) ^ rmod) * 16;  // ci chunk kq*16+khalf*8..+7
                #pragma unroll
                for (int i = 0; i < 2; ++i)
                    af[i][kq]  = *(const bf16x8*)(asmb + (wm + i * 32 + l31) * 128 + phys);
                #pragma unroll
                for (int j = 0; j < 2; ++j)
                    bfr[j][kq] = *(const bf16x8*)(bsmb + (wn + j * 32 + l31) * 128 + phys);
            }
            #pragma unroll
            for (int kq = 0; kq < 4; ++kq)
                #pragma unroll
                for (int i = 0; i < 2; ++i)
                    #pragma unroll
                    for (int j = 0; j < 2; ++j)
                        acc[i][j] = __builtin_amdgcn_mfma_f32_32x32x16_bf16(
                            af[i][kq], bfr[j][kq], acc[i][j], 0, 0, 0);
            __syncthreads();
        }
    }

    #pragma unroll
    for (int j = 0; j < 2; ++j) {
        const int pg    = pix0 + wn + j * 32 + l31;
        const int ni    = pg / PLANE;
        const int inner = pg - ni * PLANE;
        float* op = out + (size_t)ni * (COUT * PLANE) + inner;
        #pragma unroll
        for (int i = 0; i < 2; ++i) {
            #pragma unroll
            for (int g = 0; g < 4; ++g) {
                const int crow = c0 + wm + i * 32 + g * 8 + 4 * khalf;
                #pragma unroll
                for (int r = 0; r < 4; ++r)
                    op[(size_t)(crow + r) * PLANE] = acc[i][j][g * 4 + r] + bias[crow + r];
            }
        }
    }
}

extern "C" void kernel_launch(void* const* d_in, const int* in_sizes, int n_in,
                              void* d_out, int out_size, void* d_ws, size_t ws_size,
                              hipStream_t stream) {
    const float* in   = (const float*)d_in[0];
    const float* wt   = (const float*)d_in[1];
    const float* bias = (const float*)d_in[2];
    float* out        = (float*)d_out;

    unsigned short* wb = (unsigned short*)((char*)d_ws + WB_OFF);
    unsigned short* xp = (unsigned short*)((char*)d_ws + XP_OFF);

    prep<<<NXROWS + COUT, 256, 0, stream>>>(in, wt, xp, wb);

    conv_mfma<<<dim3(NWG), 256, 0, stream>>>(wb, xp, bias, out);
}